// Round 4
// baseline (2378.678 us; speedup 1.0000x reference)
//
#include <hip/hip_runtime.h>
#include <hip/hip_bf16.h>

typedef __attribute__((ext_vector_type(8))) short bf16x8;
typedef __attribute__((ext_vector_type(4))) float f32x4;
typedef __attribute__((ext_vector_type(2))) float f32x2;
typedef __attribute__((ext_vector_type(4))) unsigned u32x4;

#define EPB 4096         // edges per partition block
#define BUCKET_BITS 8
#define BUCKET_SIZE 256  // nodes per bucket
#define MAXBUCK 512

static __device__ __forceinline__ unsigned short f2bf(float f) {
    union { float f; unsigned u; } v; v.f = f;
    unsigned r = v.u + 0x7FFF + ((v.u >> 16) & 1);
    return (unsigned short)(r >> 16);
}
static __device__ __forceinline__ float asf(unsigned u) {
    union { unsigned u; float f; } v; v.u = u;
    return v.f;
}
// packed bf16 pair -> f32x2 {lo, hi}
static __device__ __forceinline__ f32x2 cvt2(unsigned u) {
    f32x2 r;
    r.x = asf(u << 16);
    r.y = asf(u & 0xFFFF0000u);
    return r;
}
static __device__ __forceinline__ unsigned pk2(float lo, float hi) {
    return ((unsigned)f2bf(hi) << 16) | f2bf(lo);
}

// ================= K1: prep — weight swizzles + edge histogram (merged) =================
__global__ __launch_bounds__(256) void prep(const float* __restrict__ Wrel1,
                                            const float* __restrict__ Wroot1,
                                            const float* __restrict__ Wrel2,
                                            const float* __restrict__ Wroot2,
                                            const float* __restrict__ Wlin,
                                            const int* __restrict__ dst,
                                            unsigned short* __restrict__ bsw1,
                                            unsigned short* __restrict__ bsw2,
                                            unsigned short* __restrict__ bswL,
                                            int* __restrict__ hist,
                                            int E, int nblk, int nbuck) {
    __shared__ int h[MAXBUCK];
    int blk = blockIdx.x, t = threadIdx.x;
    if (blk < 256) {
        const float* Wrel  = (blk < 128) ? Wrel1 : Wrel2;
        const float* Wroot = (blk < 128) ? Wroot1 : Wroot2;
        unsigned short* bsw = (blk < 128) ? bsw1 : bsw2;
        int idx = (blk & 127) * 256 + t;  // 32768 total
        int j = idx & 7, L = (idx >> 3) & 63, ct = (idx >> 9) & 15, kt = idx >> 13;
        int k = kt * 32 + ((L >> 4) * 8) + j;
        int c = ct * 16 + (L & 15);
        float v = (c < 128) ? Wrel[k * 128 + c] : Wroot[k * 128 + (c - 128)];
        bsw[idx] = f2bf(v);
    } else if (blk < 304) {
        int idx = (blk - 256) * 256 + t;  // 12288 total
        int tt = idx;
        int j = tt & 7; tt >>= 3;
        int L = tt & 63; tt >>= 6;
        int ct = tt % 3;
        int kt = tt / 3;
        int k = kt * 32 + ((L >> 4) * 8) + j;
        int c = ct * 16 + (L & 15);
        float v = (c < 40) ? Wlin[k * 40 + c] : 0.f;
        bswL[idx] = f2bf(v);
    } else {
        int hb = blk - 304;
        for (int i = t; i < MAXBUCK; i += 256) h[i] = 0;
        __syncthreads();
        int e0 = hb * EPB;
#pragma unroll
        for (int it = 0; it < EPB / 256; it++) {
            int e = e0 + it * 256 + t;
            if (e < E) atomicAdd(&h[dst[e] >> BUCKET_BITS], 1);
        }
        __syncthreads();
        for (int i = t; i < nbuck; i += 256) hist[i * nblk + hb] = h[i];
    }
}

// ================= K2a: bucket totals =================
__global__ __launch_bounds__(256) void bucket_total(const int* __restrict__ hist,
                                                    int* __restrict__ total, int nblk) {
    __shared__ int s[256];
    int b = blockIdx.x, t = threadIdx.x;
    int v = 0;
    for (int i = t; i < nblk; i += 256) v += hist[b * nblk + i];
    s[t] = v; __syncthreads();
#pragma unroll
    for (int o = 128; o >= 1; o >>= 1) {
        if (t < o) s[t] += s[t + o];
        __syncthreads();
    }
    if (t == 0) total[b] = s[0];
}

// ================= K2b: exclusive scan of bucket totals (pair-scan, nbuck <= 512) =================
__global__ __launch_bounds__(256) void bucket_scan(const int* __restrict__ total,
                                                   int* __restrict__ base, int nbuck) {
    __shared__ int s[256];
    int t = threadIdx.x;
    int e0 = (2 * t < nbuck) ? total[2 * t] : 0;
    int e1 = (2 * t + 1 < nbuck) ? total[2 * t + 1] : 0;
    int ps = e0 + e1;
    s[t] = ps; __syncthreads();
#pragma unroll
    for (int o = 1; o < 256; o <<= 1) {
        int x = (t >= o) ? s[t - o] : 0;
        __syncthreads();
        s[t] += x; __syncthreads();
    }
    int pbase = s[t] - ps;
    if (2 * t <= nbuck) base[2 * t] = pbase;
    if (2 * t + 1 <= nbuck) base[2 * t + 1] = pbase + e0;
}

// ================= K2c: per-bucket scan over blocks -> global slot bases (in place) =================
__global__ __launch_bounds__(256) void block_scan(int* __restrict__ hist,
                                                  const int* __restrict__ base, int nblk) {
    __shared__ int s[256];
    int b = blockIdx.x, t = threadIdx.x;
    int carryv = base[b];
    for (int start = 0; start < nblk; start += 256) {
        int i = start + t;
        int v = (i < nblk) ? hist[b * nblk + i] : 0;
        s[t] = v; __syncthreads();
#pragma unroll
        for (int o = 1; o < 256; o <<= 1) {
            int x = (t >= o) ? s[t - o] : 0;
            __syncthreads();
            s[t] += x; __syncthreads();
        }
        int excl = s[t] - v + carryv;
        if (i < nblk) hist[b * nblk + i] = excl;
        carryv += s[255];
        __syncthreads();
    }
}

// ================= K3: per-chunk LDS counting sort -> bucket-sorted packed records =================
__global__ __launch_bounds__(256) void edge_part(const int* __restrict__ src,
                                                 const int* __restrict__ dst,
                                                 const int* __restrict__ hist,  // block bases
                                                 int* __restrict__ part,
                                                 int E, int nblk, int nbuck) {
    __shared__ int hcnt[MAXBUCK];
    __shared__ int lstart[MAXBUCK];
    __shared__ int cur[MAXBUCK];
    __shared__ int gbase[MAXBUCK];
    __shared__ int s2[256];
    __shared__ int sdst[EPB];  // 16 KB
    __shared__ int ssrc[EPB];  // 16 KB
    int t = threadIdx.x, blk = blockIdx.x;
    int e0 = blk * EPB;
    int cnt = E - e0; if (cnt > EPB) cnt = EPB;
    for (int i = t; i < MAXBUCK; i += 256) hcnt[i] = 0;
    for (int i = t; i < nbuck; i += 256) gbase[i] = hist[i * nblk + blk];
    __syncthreads();
    int myd[EPB / 256], mys[EPB / 256];
#pragma unroll
    for (int it = 0; it < EPB / 256; it++) {
        int i = it * 256 + t;
        if (i < cnt) {
            myd[it] = dst[e0 + i];
            mys[it] = src[e0 + i];
            atomicAdd(&hcnt[myd[it] >> BUCKET_BITS], 1);
        }
    }
    __syncthreads();
    int p0 = hcnt[2 * t], p1 = hcnt[2 * t + 1];
    int ps = p0 + p1;
    s2[t] = ps; __syncthreads();
#pragma unroll
    for (int o = 1; o < 256; o <<= 1) {
        int x = (t >= o) ? s2[t - o] : 0;
        __syncthreads();
        s2[t] += x; __syncthreads();
    }
    int pbase = s2[t] - ps;
    lstart[2 * t] = pbase; lstart[2 * t + 1] = pbase + p0;
    cur[2 * t] = 0; cur[2 * t + 1] = 0;
    __syncthreads();
#pragma unroll
    for (int it = 0; it < EPB / 256; it++) {
        int i = it * 256 + t;
        if (i < cnt) {
            int b = myd[it] >> BUCKET_BITS;
            int p = lstart[b] + atomicAdd(&cur[b], 1);
            sdst[p] = myd[it];
            ssrc[p] = mys[it];
        }
    }
    __syncthreads();
    for (int i = t; i < cnt; i += 256) {
        int d = sdst[i], s = ssrc[i];
        int b = d >> BUCKET_BITS;
        part[gbase[b] + (i - lstart[b])] = ((d & (BUCKET_SIZE - 1)) << 17) | s;
    }
}

// ================= K4: layer-1 GEMM (x f32 -> bf16 fragments, sliced outputs) =================
// xr/accbf written in XCD-sliced layout: [slice(8)][node(N)][16 features]
__global__ __launch_bounds__(256) void gemm_layer1(const float* __restrict__ x,
                                                   const unsigned short* __restrict__ Bsw,
                                                   const float* __restrict__ bias,
                                                   unsigned short* __restrict__ xr,
                                                   unsigned short* __restrict__ accbf,
                                                   int N) {
    int t = threadIdx.x;
    int wid = blockIdx.x * 4 + (t >> 6);
    int L = t & 63;
    int r0 = wid * 16;
    if (r0 >= N) return;
    int arow = r0 + (L & 15);
    const bf16x8* Bptr = ((const bf16x8*)Bsw) + L;
    f32x4 acc[16];
#pragma unroll
    for (int i = 0; i < 16; i++) acc[i] = (f32x4){0.f, 0.f, 0.f, 0.f};
#pragma unroll
    for (int kt = 0; kt < 4; kt++) {
        const float* Arow = x + (size_t)arow * 128 + ((L >> 4) * 8) + kt * 32;
        float4 a0 = *(const float4*)Arow;
        float4 a1 = *(const float4*)(Arow + 4);
        bf16x8 a;
        a[0] = (short)f2bf(a0.x); a[1] = (short)f2bf(a0.y);
        a[2] = (short)f2bf(a0.z); a[3] = (short)f2bf(a0.w);
        a[4] = (short)f2bf(a1.x); a[5] = (short)f2bf(a1.y);
        a[6] = (short)f2bf(a1.z); a[7] = (short)f2bf(a1.w);
#pragma unroll
        for (int ct = 0; ct < 16; ct++) {
            bf16x8 b = Bptr[(kt * 16 + ct) * 64];
            acc[ct] = __builtin_amdgcn_mfma_f32_16x16x32_bf16(a, b, acc[ct], 0, 0, 0);
        }
    }
    int rbase = r0 + (L >> 4) * 4;
    int cl = L & 15;
#pragma unroll
    for (int ct = 0; ct < 16; ct++) {
#pragma unroll
        for (int r = 0; r < 4; r++) {
            int row = rbase + r;
            float v = acc[ct][r];
            if (ct < 8)
                xr[((size_t)ct * N + row) * 16 + cl] = f2bf(v);
            else
                accbf[((size_t)(ct - 8) * N + row) * 16 + cl] =
                    f2bf(v + bias[(ct - 8) * 16 + cl]);
        }
    }
}

// ================= layer-2 GEMM (bf16 A sliced, B staged in LDS, grid-stride tiles) =================
__global__ __launch_bounds__(256) void gemm_layer2(const unsigned short* __restrict__ Abf,
                                                   const unsigned short* __restrict__ Bsw,
                                                   const float* __restrict__ bias,
                                                   unsigned short* __restrict__ xr,
                                                   unsigned short* __restrict__ accbf, int N) {
    __shared__ unsigned short Bs[32768];  // 64 KB
    int t = threadIdx.x;
    {
        uint4* d4 = (uint4*)Bs;
        const uint4* s4 = (const uint4*)Bsw;
#pragma unroll
        for (int i = 0; i < 16; i++) d4[t + i * 256] = s4[t + i * 256];
    }
    __syncthreads();
    int w = t >> 6, L = t & 63;
    int nTiles = (N + 15) / 16;
    for (int tile = blockIdx.x * 4 + w; tile < nTiles; tile += gridDim.x * 4) {
        int r0 = tile * 16;
        int arow = r0 + (L & 15);
        f32x4 acc[16];
#pragma unroll
        for (int i = 0; i < 16; i++) acc[i] = (f32x4){0.f, 0.f, 0.f, 0.f};
#pragma unroll
        for (int kt = 0; kt < 4; kt++) {
            int k0 = (L >> 4) * 8 + kt * 32;
            bf16x8 a = *((const bf16x8*)(Abf + ((size_t)(k0 >> 4) * N + arow) * 16 + (k0 & 15)));
#pragma unroll
            for (int ct = 0; ct < 16; ct++) {
                bf16x8 b = *(const bf16x8*)(Bs + (((kt * 16 + ct) * 64) + L) * 8);
                acc[ct] = __builtin_amdgcn_mfma_f32_16x16x32_bf16(a, b, acc[ct], 0, 0, 0);
            }
        }
        int rbase = r0 + (L >> 4) * 4;
        int cl = L & 15;
#pragma unroll
        for (int ct = 0; ct < 16; ct++) {
#pragma unroll
            for (int r = 0; r < 4; r++) {
                int row = rbase + r;
                float v = acc[ct][r];
                if (ct < 8)
                    xr[((size_t)ct * N + row) * 16 + cl] = f2bf(v);
                else
                    accbf[((size_t)(ct - 8) * N + row) * 16 + cl] =
                        f2bf(v + bias[(ct - 8) * 16 + cl]);
            }
        }
    }
}

// ================= edge-parallel gather-aggregate into LDS, + relu + bf16 convert =================
// block = (bucket, slice): slice = blockIdx.x & 7 (XCD-pinned), bucket = blockIdx.x >> 3.
// LDS: 256 nodes x 16 feats f32 accumulator, XOR-rotated (slot = f ^ (dl&15)) for bank spread.
// Streams part[] records (coalesced, 2 lanes/edge), gathers 32B payload (L2-hit),
// 8 fire-and-forget ds_add_f32 per lane. Epilogue: +root, relu, bf16, store.
__global__ __launch_bounds__(256) void agg_bucket(const unsigned short* __restrict__ xr,
                                                  const unsigned short* __restrict__ accbf,
                                                  const int* __restrict__ part,
                                                  const int* __restrict__ bucketBase,
                                                  unsigned short* __restrict__ out, int N) {
    __shared__ float acc[BUCKET_SIZE * 16];  // 16 KB
    int s = blockIdx.x & 7;
    int b = blockIdx.x >> 3;
    int t = threadIdx.x;
    {
        f32x4* a4 = (f32x4*)acc;
#pragma unroll
        for (int i = 0; i < 4; i++) a4[t + i * 256] = (f32x4){0.f, 0.f, 0.f, 0.f};
    }
    __syncthreads();
    int lo = bucketBase[b], hi = bucketBase[b + 1];
    const unsigned short* xrs = xr + (size_t)s * N * 16;
    int half = t & 1;
    int f0 = half * 8;
    for (int i = lo + (t >> 1); i < hi; i += 128) {
        int rec = part[i];
        int srcn = rec & 0x1FFFF;
        int dl = rec >> 17;
        uint4 p = *(const uint4*)(xrs + (size_t)srcn * 16 + f0);
        float* ab = acc + (dl << 4);
        int r = dl & 15;
        f32x2 v0 = cvt2(p.x), v1 = cvt2(p.y), v2 = cvt2(p.z), v3 = cvt2(p.w);
        atomicAdd(ab + ((f0 + 0) ^ r), v0.x);
        atomicAdd(ab + ((f0 + 1) ^ r), v0.y);
        atomicAdd(ab + ((f0 + 2) ^ r), v1.x);
        atomicAdd(ab + ((f0 + 3) ^ r), v1.y);
        atomicAdd(ab + ((f0 + 4) ^ r), v2.x);
        atomicAdd(ab + ((f0 + 5) ^ r), v2.y);
        atomicAdd(ab + ((f0 + 6) ^ r), v3.x);
        atomicAdd(ab + ((f0 + 7) ^ r), v3.y);
    }
    __syncthreads();
    int node = b * BUCKET_SIZE + t;
    if (node >= N) return;
    int r = t & 15;
    const float* ab = acc + (t << 4);
    size_t nodeOff = ((size_t)s * N + node) * 16;
    u32x4 a0 = __builtin_nontemporal_load((const u32x4*)(accbf + nodeOff));
    u32x4 a1 = __builtin_nontemporal_load((const u32x4*)(accbf + nodeOff + 8));
    u32x4 o0, o1;
    f32x2 c;
    c = cvt2(a0.x); o0.x = pk2(fmaxf(ab[0 ^ r] + c.x, 0.f),  fmaxf(ab[1 ^ r] + c.y, 0.f));
    c = cvt2(a0.y); o0.y = pk2(fmaxf(ab[2 ^ r] + c.x, 0.f),  fmaxf(ab[3 ^ r] + c.y, 0.f));
    c = cvt2(a0.z); o0.z = pk2(fmaxf(ab[4 ^ r] + c.x, 0.f),  fmaxf(ab[5 ^ r] + c.y, 0.f));
    c = cvt2(a0.w); o0.w = pk2(fmaxf(ab[6 ^ r] + c.x, 0.f),  fmaxf(ab[7 ^ r] + c.y, 0.f));
    c = cvt2(a1.x); o1.x = pk2(fmaxf(ab[8 ^ r] + c.x, 0.f),  fmaxf(ab[9 ^ r] + c.y, 0.f));
    c = cvt2(a1.y); o1.y = pk2(fmaxf(ab[10 ^ r] + c.x, 0.f), fmaxf(ab[11 ^ r] + c.y, 0.f));
    c = cvt2(a1.z); o1.z = pk2(fmaxf(ab[12 ^ r] + c.x, 0.f), fmaxf(ab[13 ^ r] + c.y, 0.f));
    c = cvt2(a1.w); o1.w = pk2(fmaxf(ab[14 ^ r] + c.x, 0.f), fmaxf(ab[15 ^ r] + c.y, 0.f));
    __builtin_nontemporal_store(o0, (u32x4*)(out + nodeOff));
    __builtin_nontemporal_store(o1, (u32x4*)(out + nodeOff + 8));
}

// ================= final GEMM + fused log_softmax (B in LDS, grid-stride, sliced A) =================
__global__ __launch_bounds__(256) void gemm_final_ls(const unsigned short* __restrict__ x1bf,
                                                     const unsigned short* __restrict__ x2bf,
                                                     const unsigned short* __restrict__ Bsw,
                                                     const float* __restrict__ blin,
                                                     float* __restrict__ out, int N) {
    __shared__ unsigned short Bs[12288];  // 24 KB
    int t = threadIdx.x;
    {
        uint4* d4 = (uint4*)Bs;
        const uint4* s4 = (const uint4*)Bsw;
#pragma unroll
        for (int i = 0; i < 6; i++) d4[t + i * 256] = s4[t + i * 256];
    }
    __syncthreads();
    int w = t >> 6, L = t & 63;
    int cl = L & 15;
    float b0 = blin[cl], b1 = blin[16 + cl];
    float b2 = (cl < 8) ? blin[32 + cl] : 0.f;
    int nTiles = (N + 15) / 16;
    for (int tile = blockIdx.x * 4 + w; tile < nTiles; tile += gridDim.x * 4) {
        int r0 = tile * 16;
        int arow = r0 + (L & 15);
        f32x4 acc[3];
#pragma unroll
        for (int i = 0; i < 3; i++) acc[i] = (f32x4){0.f, 0.f, 0.f, 0.f};
#pragma unroll
        for (int kt = 0; kt < 8; kt++) {
            const unsigned short* Ab = (kt < 4) ? x1bf : x2bf;
            int kk = (kt & 3) * 32 + ((L >> 4) * 8);
            bf16x8 a = *((const bf16x8*)(Ab + ((size_t)(kk >> 4) * N + arow) * 16 + (kk & 15)));
#pragma unroll
            for (int ct = 0; ct < 3; ct++) {
                bf16x8 b = *(const bf16x8*)(Bs + (((kt * 3 + ct) * 64) + L) * 8);
                acc[ct] = __builtin_amdgcn_mfma_f32_16x16x32_bf16(a, b, acc[ct], 0, 0, 0);
            }
        }
        int rbase = r0 + (L >> 4) * 4;
#pragma unroll
        for (int r = 0; r < 4; r++) {
            int row = rbase + r;
            float v0 = acc[0][r] + b0;
            float v1 = acc[1][r] + b1;
            float v2 = (cl < 8) ? (acc[2][r] + b2) : -__builtin_inff();
            float m = fmaxf(fmaxf(v0, v1), v2);
#pragma unroll
            for (int off = 8; off >= 1; off >>= 1) m = fmaxf(m, __shfl_xor(m, off, 64));
            float e = __expf(v0 - m) + __expf(v1 - m) + ((cl < 8) ? __expf(v2 - m) : 0.f);
#pragma unroll
            for (int off = 8; off >= 1; off >>= 1) e += __shfl_xor(e, off, 64);
            float ls = m + __logf(e);
            float* op = out + (size_t)row * 40;
            op[cl] = v0 - ls;
            op[16 + cl] = v1 - ls;
            if (cl < 8) op[32 + cl] = v2 - ls;
        }
    }
}

extern "C" void kernel_launch(void* const* d_in, const int* in_sizes, int n_in,
                              void* d_out, int out_size, void* d_ws, size_t ws_size,
                              hipStream_t stream) {
    const float* x      = (const float*)d_in[0];
    const int*   edge   = (const int*)d_in[1];
    const float* Wrel1  = (const float*)d_in[2];
    const float* brel1  = (const float*)d_in[3];
    const float* Wroot1 = (const float*)d_in[4];
    const float* Wrel2  = (const float*)d_in[5];
    const float* brel2  = (const float*)d_in[6];
    const float* Wroot2 = (const float*)d_in[7];
    const float* Wlin   = (const float*)d_in[8];
    const float* blin   = (const float*)d_in[9];

    const int N = in_sizes[0] / 128;
    const int E = in_sizes[1] / 2;
    const int* src = edge;
    const int* dst = edge + E;

    const int nblk  = (E + EPB - 1) / EPB;                    // 391
    const int nbuck = (N + BUCKET_SIZE - 1) / BUCKET_SIZE;    // 391

    char* ws = (char*)d_ws;
    size_t off = 0;
    auto alloc = [&](size_t bytes) -> void* {
        void* p = ws + off;
        off += (bytes + 255) & ~(size_t)255;
        return p;
    };
    unsigned short* x1bf = (unsigned short*)alloc((size_t)N * 128 * 2);
    unsigned short* x2bf = (unsigned short*)alloc((size_t)N * 128 * 2);
    unsigned short* xr   = (unsigned short*)alloc((size_t)N * 128 * 2);
    unsigned short* accbf= (unsigned short*)alloc((size_t)N * 128 * 2);
    unsigned short* bsw1 = (unsigned short*)alloc(32768 * 2);
    unsigned short* bsw2 = (unsigned short*)alloc(32768 * 2);
    unsigned short* bswL = (unsigned short*)alloc(12288 * 2);
    int* hist       = (int*)alloc((size_t)nbuck * nblk * 4);
    int* bucketTot  = (int*)alloc((size_t)nbuck * 4);
    int* bucketBase = (int*)alloc((size_t)(nbuck + 1) * 4);
    int* part       = (int*)alloc((size_t)E * 4);

    const int rowTiles = (N + 15) / 16;
    const int gemmBlocks = (rowTiles + 3) / 4;
    const int aggBlocks = nbuck * 8;  // (bucket, slice) -> slice pinned to XCD

    // K1: weight swizzles + edge histogram
    prep<<<304 + nblk, 256, 0, stream>>>(Wrel1, Wroot1, Wrel2, Wroot2, Wlin, dst,
                                         bsw1, bsw2, bswL, hist, E, nblk, nbuck);
    // K2: scans
    bucket_total<<<nbuck, 256, 0, stream>>>(hist, bucketTot, nblk);
    bucket_scan<<<1, 256, 0, stream>>>(bucketTot, bucketBase, nbuck);
    block_scan<<<nbuck, 256, 0, stream>>>(hist, bucketBase, nblk);
    // K3: partition (bucket-sorted records with local-dst + src)
    edge_part<<<nblk, 256, 0, stream>>>(src, dst, hist, part, E, nblk, nbuck);
    // K4: layer-1 GEMM
    gemm_layer1<<<gemmBlocks, 256, 0, stream>>>(x, bsw1, brel1, xr, accbf, N);
    // K5: layer-1 aggregation (edge-parallel, LDS accumulate)
    agg_bucket<<<aggBlocks, 256, 0, stream>>>(xr, accbf, part, bucketBase, x1bf, N);
    // K6: layer-2 GEMM (B in LDS, grid-stride)
    gemm_layer2<<<512, 256, 0, stream>>>(x1bf, bsw2, brel2, xr, accbf, N);
    // K7: layer-2 aggregation
    agg_bucket<<<aggBlocks, 256, 0, stream>>>(xr, accbf, part, bucketBase, x2bf, N);
    // K8: classifier + fused log_softmax (B in LDS, grid-stride)
    gemm_final_ls<<<512, 256, 0, stream>>>(x1bf, x2bf, bswL, blin, (float*)d_out, N);
}

// Round 6
// 653.775 us; speedup vs baseline: 3.6384x; 3.6384x over previous
//
#include <hip/hip_runtime.h>
#include <hip/hip_bf16.h>

typedef __attribute__((ext_vector_type(8))) short bf16x8;
typedef __attribute__((ext_vector_type(4))) float f32x4;
typedef __attribute__((ext_vector_type(2))) float f32x2;

#define EPB 4096         // edges per partition block
#define BUCKET_BITS 8
#define BUCKET_SIZE 256  // nodes per bucket
#define MAXBUCK 512

static __device__ __forceinline__ unsigned short f2bf(float f) {
    union { float f; unsigned u; } v; v.f = f;
    unsigned r = v.u + 0x7FFF + ((v.u >> 16) & 1);
    return (unsigned short)(r >> 16);
}
static __device__ __forceinline__ float asf(unsigned u) {
    union { unsigned u; float f; } v; v.u = u;
    return v.f;
}
// packed bf16 pair -> f32x2 {lo, hi}
static __device__ __forceinline__ f32x2 cvt2(unsigned u) {
    f32x2 r;
    r.x = asf(u << 16);
    r.y = asf(u & 0xFFFF0000u);
    return r;
}
static __device__ __forceinline__ unsigned pk2(float lo, float hi) {
    return ((unsigned)f2bf(hi) << 16) | f2bf(lo);
}

// ================= K1: prep — weight swizzles + edge histogram (merged) =================
__global__ __launch_bounds__(256) void prep(const float* __restrict__ Wrel1,
                                            const float* __restrict__ Wroot1,
                                            const float* __restrict__ Wrel2,
                                            const float* __restrict__ Wroot2,
                                            const float* __restrict__ Wlin,
                                            const int* __restrict__ dst,
                                            unsigned short* __restrict__ bsw1,
                                            unsigned short* __restrict__ bsw2,
                                            unsigned short* __restrict__ bswL,
                                            int* __restrict__ hist,
                                            int E, int nblk, int nbuck) {
    __shared__ int h[MAXBUCK];
    int blk = blockIdx.x, t = threadIdx.x;
    if (blk < 256) {
        const float* Wrel  = (blk < 128) ? Wrel1 : Wrel2;
        const float* Wroot = (blk < 128) ? Wroot1 : Wroot2;
        unsigned short* bsw = (blk < 128) ? bsw1 : bsw2;
        int idx = (blk & 127) * 256 + t;  // 32768 total
        int j = idx & 7, L = (idx >> 3) & 63, ct = (idx >> 9) & 15, kt = idx >> 13;
        int k = kt * 32 + ((L >> 4) * 8) + j;
        int c = ct * 16 + (L & 15);
        float v = (c < 128) ? Wrel[k * 128 + c] : Wroot[k * 128 + (c - 128)];
        bsw[idx] = f2bf(v);
    } else if (blk < 304) {
        int idx = (blk - 256) * 256 + t;  // 12288 total
        int tt = idx;
        int j = tt & 7; tt >>= 3;
        int L = tt & 63; tt >>= 6;
        int ct = tt % 3;
        int kt = tt / 3;
        int k = kt * 32 + ((L >> 4) * 8) + j;
        int c = ct * 16 + (L & 15);
        float v = (c < 40) ? Wlin[k * 40 + c] : 0.f;
        bswL[idx] = f2bf(v);
    } else {
        int hb = blk - 304;
        for (int i = t; i < MAXBUCK; i += 256) h[i] = 0;
        __syncthreads();
        int e0 = hb * EPB;
#pragma unroll
        for (int it = 0; it < EPB / 256; it++) {
            int e = e0 + it * 256 + t;
            if (e < E) atomicAdd(&h[dst[e] >> BUCKET_BITS], 1);
        }
        __syncthreads();
        for (int i = t; i < nbuck; i += 256) hist[i * nblk + hb] = h[i];
    }
}

// ================= K2a: bucket totals =================
__global__ __launch_bounds__(256) void bucket_total(const int* __restrict__ hist,
                                                    int* __restrict__ total, int nblk) {
    __shared__ int s[256];
    int b = blockIdx.x, t = threadIdx.x;
    int v = 0;
    for (int i = t; i < nblk; i += 256) v += hist[b * nblk + i];
    s[t] = v; __syncthreads();
#pragma unroll
    for (int o = 128; o >= 1; o >>= 1) {
        if (t < o) s[t] += s[t + o];
        __syncthreads();
    }
    if (t == 0) total[b] = s[0];
}

// ================= K2b: exclusive scan of bucket totals (pair-scan, nbuck <= 512) =================
__global__ __launch_bounds__(256) void bucket_scan(const int* __restrict__ total,
                                                   int* __restrict__ base, int nbuck) {
    __shared__ int s[256];
    int t = threadIdx.x;
    int e0 = (2 * t < nbuck) ? total[2 * t] : 0;
    int e1 = (2 * t + 1 < nbuck) ? total[2 * t + 1] : 0;
    int ps = e0 + e1;
    s[t] = ps; __syncthreads();
#pragma unroll
    for (int o = 1; o < 256; o <<= 1) {
        int x = (t >= o) ? s[t - o] : 0;
        __syncthreads();
        s[t] += x; __syncthreads();
    }
    int pbase = s[t] - ps;
    if (2 * t <= nbuck) base[2 * t] = pbase;
    if (2 * t + 1 <= nbuck) base[2 * t + 1] = pbase + e0;
}

// ================= K2c: per-bucket scan over blocks -> global slot bases (in place) =================
__global__ __launch_bounds__(256) void block_scan(int* __restrict__ hist,
                                                  const int* __restrict__ base, int nblk) {
    __shared__ int s[256];
    int b = blockIdx.x, t = threadIdx.x;
    int carryv = base[b];
    for (int start = 0; start < nblk; start += 256) {
        int i = start + t;
        int v = (i < nblk) ? hist[b * nblk + i] : 0;
        s[t] = v; __syncthreads();
#pragma unroll
        for (int o = 1; o < 256; o <<= 1) {
            int x = (t >= o) ? s[t - o] : 0;
            __syncthreads();
            s[t] += x; __syncthreads();
        }
        int excl = s[t] - v + carryv;
        if (i < nblk) hist[b * nblk + i] = excl;
        carryv += s[255];
        __syncthreads();
    }
}

// ================= K3: per-chunk LDS counting sort -> bucket-sorted packed records =================
__global__ __launch_bounds__(256) void edge_part(const int* __restrict__ src,
                                                 const int* __restrict__ dst,
                                                 const int* __restrict__ hist,  // block bases
                                                 int* __restrict__ part,
                                                 int E, int nblk, int nbuck) {
    __shared__ int hcnt[MAXBUCK];
    __shared__ int lstart[MAXBUCK];
    __shared__ int cur[MAXBUCK];
    __shared__ int gbase[MAXBUCK];
    __shared__ int s2[256];
    __shared__ int sdst[EPB];  // 16 KB
    __shared__ int ssrc[EPB];  // 16 KB
    int t = threadIdx.x, blk = blockIdx.x;
    int e0 = blk * EPB;
    int cnt = E - e0; if (cnt > EPB) cnt = EPB;
    for (int i = t; i < MAXBUCK; i += 256) hcnt[i] = 0;
    for (int i = t; i < nbuck; i += 256) gbase[i] = hist[i * nblk + blk];
    __syncthreads();
    int myd[EPB / 256], mys[EPB / 256];
#pragma unroll
    for (int it = 0; it < EPB / 256; it++) {
        int i = it * 256 + t;
        if (i < cnt) {
            myd[it] = dst[e0 + i];
            mys[it] = src[e0 + i];
            atomicAdd(&hcnt[myd[it] >> BUCKET_BITS], 1);
        }
    }
    __syncthreads();
    int p0 = hcnt[2 * t], p1 = hcnt[2 * t + 1];
    int ps = p0 + p1;
    s2[t] = ps; __syncthreads();
#pragma unroll
    for (int o = 1; o < 256; o <<= 1) {
        int x = (t >= o) ? s2[t - o] : 0;
        __syncthreads();
        s2[t] += x; __syncthreads();
    }
    int pbase = s2[t] - ps;
    lstart[2 * t] = pbase; lstart[2 * t + 1] = pbase + p0;
    cur[2 * t] = 0; cur[2 * t + 1] = 0;
    __syncthreads();
#pragma unroll
    for (int it = 0; it < EPB / 256; it++) {
        int i = it * 256 + t;
        if (i < cnt) {
            int b = myd[it] >> BUCKET_BITS;
            int p = lstart[b] + atomicAdd(&cur[b], 1);
            sdst[p] = myd[it];
            ssrc[p] = mys[it];
        }
    }
    __syncthreads();
    for (int i = t; i < cnt; i += 256) {
        int d = sdst[i], s = ssrc[i];
        int b = d >> BUCKET_BITS;
        part[gbase[b] + (i - lstart[b])] = ((d & (BUCKET_SIZE - 1)) << 17) | s;
    }
}

// ================= K4: csr_finalize (blocks 0..nbuck-1) + layer-1 GEMM (rest), merged =================
// xr/accbf written in XCD-sliced layout: [slice(8)][node(N)][16 features]
__global__ __launch_bounds__(256) void csrfin_gemm1(const int* __restrict__ part,
                                                    const int* __restrict__ bucketBase,
                                                    int* __restrict__ off_,
                                                    int* __restrict__ deg_,
                                                    int* __restrict__ csr_src,
                                                    const float* __restrict__ x,
                                                    const unsigned short* __restrict__ Bsw,
                                                    const float* __restrict__ bias,
                                                    unsigned short* __restrict__ xr,
                                                    unsigned short* __restrict__ accbf,
                                                    int N, int nbuck) {
    __shared__ int cur[BUCKET_SIZE];
    __shared__ int h[BUCKET_SIZE];
    __shared__ int tsum[256];
    int t = threadIdx.x;
    if (blockIdx.x < (unsigned)nbuck) {
        int b = blockIdx.x;
        int lo = bucketBase[b], hi = bucketBase[b + 1];
        int n0 = b * BUCKET_SIZE;
        h[t] = 0;
        __syncthreads();
        for (int i = lo + t; i < hi; i += 256) atomicAdd(&h[part[i] >> 17], 1);
        __syncthreads();
        int hv = h[t];
        tsum[t] = hv;
        __syncthreads();
#pragma unroll
        for (int o = 1; o < 256; o <<= 1) {
            int xx = (t >= o) ? tsum[t - o] : 0;
            __syncthreads();
            tsum[t] += xx;
            __syncthreads();
        }
        int st = tsum[t] - hv;
        cur[t] = st;
        int node = n0 + t;
        if (node < N) { off_[node] = lo + st; deg_[node] = hv; }
        __syncthreads();
        for (int i = lo + t; i < hi; i += 256) {
            int rec = part[i];
            int p = atomicAdd(&cur[rec >> 17], 1);
            csr_src[lo + p] = rec & 0x1FFFF;
        }
    } else {
        int wid = (blockIdx.x - nbuck) * 4 + (t >> 6);
        int L = t & 63;
        int r0 = wid * 16;
        if (r0 >= N) return;
        int arow = r0 + (L & 15);
        const bf16x8* Bptr = ((const bf16x8*)Bsw) + L;
        f32x4 acc[16];
#pragma unroll
        for (int i = 0; i < 16; i++) acc[i] = (f32x4){0.f, 0.f, 0.f, 0.f};
#pragma unroll
        for (int kt = 0; kt < 4; kt++) {
            const float* Arow = x + (size_t)arow * 128 + ((L >> 4) * 8) + kt * 32;
            float4 a0 = *(const float4*)Arow;
            float4 a1 = *(const float4*)(Arow + 4);
            bf16x8 a;
            a[0] = (short)f2bf(a0.x); a[1] = (short)f2bf(a0.y);
            a[2] = (short)f2bf(a0.z); a[3] = (short)f2bf(a0.w);
            a[4] = (short)f2bf(a1.x); a[5] = (short)f2bf(a1.y);
            a[6] = (short)f2bf(a1.z); a[7] = (short)f2bf(a1.w);
#pragma unroll
            for (int ct = 0; ct < 16; ct++) {
                bf16x8 b = Bptr[(kt * 16 + ct) * 64];
                acc[ct] = __builtin_amdgcn_mfma_f32_16x16x32_bf16(a, b, acc[ct], 0, 0, 0);
            }
        }
        int rbase = r0 + (L >> 4) * 4;
        int cl = L & 15;
#pragma unroll
        for (int ct = 0; ct < 16; ct++) {
#pragma unroll
            for (int r = 0; r < 4; r++) {
                int row = rbase + r;
                float v = acc[ct][r];
                if (ct < 8)
                    xr[((size_t)ct * N + row) * 16 + cl] = f2bf(v);
                else
                    accbf[((size_t)(ct - 8) * N + row) * 16 + cl] =
                        f2bf(v + bias[(ct - 8) * 16 + cl]);
            }
        }
    }
}

// ================= layer-2 GEMM (bf16 A sliced, B staged in LDS, grid-stride tiles) =================
__global__ __launch_bounds__(256) void gemm_layer2(const unsigned short* __restrict__ Abf,
                                                   const unsigned short* __restrict__ Bsw,
                                                   const float* __restrict__ bias,
                                                   unsigned short* __restrict__ xr,
                                                   unsigned short* __restrict__ accbf, int N) {
    __shared__ unsigned short Bs[32768];  // 64 KB
    int t = threadIdx.x;
    {
        uint4* d4 = (uint4*)Bs;
        const uint4* s4 = (const uint4*)Bsw;
#pragma unroll
        for (int i = 0; i < 16; i++) d4[t + i * 256] = s4[t + i * 256];
    }
    __syncthreads();
    int w = t >> 6, L = t & 63;
    int nTiles = (N + 15) / 16;
    for (int tile = blockIdx.x * 4 + w; tile < nTiles; tile += gridDim.x * 4) {
        int r0 = tile * 16;
        int arow = r0 + (L & 15);
        f32x4 acc[16];
#pragma unroll
        for (int i = 0; i < 16; i++) acc[i] = (f32x4){0.f, 0.f, 0.f, 0.f};
#pragma unroll
        for (int kt = 0; kt < 4; kt++) {
            int k0 = (L >> 4) * 8 + kt * 32;
            bf16x8 a = *((const bf16x8*)(Abf + ((size_t)(k0 >> 4) * N + arow) * 16 + (k0 & 15)));
#pragma unroll
            for (int ct = 0; ct < 16; ct++) {
                bf16x8 b = *(const bf16x8*)(Bs + (((kt * 16 + ct) * 64) + L) * 8);
                acc[ct] = __builtin_amdgcn_mfma_f32_16x16x32_bf16(a, b, acc[ct], 0, 0, 0);
            }
        }
        int rbase = r0 + (L >> 4) * 4;
        int cl = L & 15;
#pragma unroll
        for (int ct = 0; ct < 16; ct++) {
#pragma unroll
            for (int r = 0; r < 4; r++) {
                int row = rbase + r;
                float v = acc[ct][r];
                if (ct < 8)
                    xr[((size_t)ct * N + row) * 16 + cl] = f2bf(v);
                else
                    accbf[((size_t)(ct - 8) * N + row) * 16 + cl] =
                        f2bf(v + bias[(ct - 8) * 16 + cl]);
            }
        }
    }
}

// ================= gather-aggregate + relu + bf16 — XCD-sliced, wide-MLP =================
// One wave per (node, slice). slice = blockIdx.x & 7 (XCD-pinned L2 residency).
// 8 groups of 8 lanes; group g handles edges k+g; lane loads one dword (2 feats) of the
// 32B slice row. Main loop step 16 w/ 2 accumulators -> an avg-degree node's whole
// gather is outstanding in one latency window (R0's winning shape, on the sliced layout).
__global__ __launch_bounds__(256) void agg_sliced(const unsigned short* __restrict__ xr,
                                                  const unsigned short* __restrict__ accbf,
                                                  const int* __restrict__ off_,
                                                  const int* __restrict__ deg,
                                                  const int* __restrict__ csr_src,
                                                  unsigned short* __restrict__ out, int N) {
    int s = blockIdx.x & 7;
    int nb = blockIdx.x >> 3;
    int t = threadIdx.x;
    int node = nb * 4 + (t >> 6);
    if (node >= N) return;
    int L = t & 63;
    int g = L >> 3;   // edge group 0..7
    int f = L & 7;    // dword slot within 32B slice row
    int o = off_[node];
    int d = deg[node];
    const unsigned* xrs = (const unsigned*)(xr + (size_t)s * N * 16) + f;
    const int* ip = csr_src + o + g;  // group g reads edges k+g

    f32x2 a0 = (f32x2){0.f, 0.f}, a1 = (f32x2){0.f, 0.f};
    int k = 0;
    int d16 = (d >= 16) ? (d & ~15) : 0;
    for (; k < d16; k += 16) {
        int i0 = ip[k];
        int i1 = ip[k + 8];
        unsigned p0 = xrs[(size_t)i0 * 8];
        unsigned p1 = xrs[(size_t)i1 * 8];
        a0 += cvt2(p0);
        a1 += cvt2(p1);
    }
    for (; k < d; k += 8) {
        if (k + g < d) {
            int i0 = ip[k];
            unsigned p0 = xrs[(size_t)i0 * 8];
            a0 += cvt2(p0);
        }
    }
    a0 += a1;
    // reduce across the 8 groups (lane bits 3..5)
    a0.x += __shfl_xor(a0.x, 8, 64);  a0.y += __shfl_xor(a0.y, 8, 64);
    a0.x += __shfl_xor(a0.x, 16, 64); a0.y += __shfl_xor(a0.y, 16, 64);
    a0.x += __shfl_xor(a0.x, 32, 64); a0.y += __shfl_xor(a0.y, 32, 64);
    if (g == 0) {
        size_t nodeOff = ((size_t)s * N + node) * 16 + f * 2;
        unsigned ab = __builtin_nontemporal_load((const unsigned*)(accbf + nodeOff));
        f32x2 av = cvt2(ab);
        unsigned wv = pk2(fmaxf(av.x + a0.x, 0.f), fmaxf(av.y + a0.y, 0.f));
        __builtin_nontemporal_store(wv, (unsigned*)(out + nodeOff));
    }
}

// ================= final GEMM + fused log_softmax (B in LDS, grid-stride, sliced A) =================
__global__ __launch_bounds__(256) void gemm_final_ls(const unsigned short* __restrict__ x1bf,
                                                     const unsigned short* __restrict__ x2bf,
                                                     const unsigned short* __restrict__ Bsw,
                                                     const float* __restrict__ blin,
                                                     float* __restrict__ out, int N) {
    __shared__ unsigned short Bs[12288];  // 24 KB
    int t = threadIdx.x;
    {
        uint4* d4 = (uint4*)Bs;
        const uint4* s4 = (const uint4*)Bsw;
#pragma unroll
        for (int i = 0; i < 6; i++) d4[t + i * 256] = s4[t + i * 256];
    }
    __syncthreads();
    int w = t >> 6, L = t & 63;
    int cl = L & 15;
    float b0 = blin[cl], b1 = blin[16 + cl];
    float b2 = (cl < 8) ? blin[32 + cl] : 0.f;
    int nTiles = (N + 15) / 16;
    for (int tile = blockIdx.x * 4 + w; tile < nTiles; tile += gridDim.x * 4) {
        int r0 = tile * 16;
        int arow = r0 + (L & 15);
        f32x4 acc[3];
#pragma unroll
        for (int i = 0; i < 3; i++) acc[i] = (f32x4){0.f, 0.f, 0.f, 0.f};
#pragma unroll
        for (int kt = 0; kt < 8; kt++) {
            const unsigned short* Ab = (kt < 4) ? x1bf : x2bf;
            int kk = (kt & 3) * 32 + ((L >> 4) * 8);
            bf16x8 a = *((const bf16x8*)(Ab + ((size_t)(kk >> 4) * N + arow) * 16 + (kk & 15)));
#pragma unroll
            for (int ct = 0; ct < 3; ct++) {
                bf16x8 b = *(const bf16x8*)(Bs + (((kt * 3 + ct) * 64) + L) * 8);
                acc[ct] = __builtin_amdgcn_mfma_f32_16x16x32_bf16(a, b, acc[ct], 0, 0, 0);
            }
        }
        int rbase = r0 + (L >> 4) * 4;
#pragma unroll
        for (int r = 0; r < 4; r++) {
            int row = rbase + r;
            float v0 = acc[0][r] + b0;
            float v1 = acc[1][r] + b1;
            float v2 = (cl < 8) ? (acc[2][r] + b2) : -__builtin_inff();
            float m = fmaxf(fmaxf(v0, v1), v2);
#pragma unroll
            for (int off = 8; off >= 1; off >>= 1) m = fmaxf(m, __shfl_xor(m, off, 64));
            float e = __expf(v0 - m) + __expf(v1 - m) + ((cl < 8) ? __expf(v2 - m) : 0.f);
#pragma unroll
            for (int off = 8; off >= 1; off >>= 1) e += __shfl_xor(e, off, 64);
            float ls = m + __logf(e);
            float* op = out + (size_t)row * 40;
            op[cl] = v0 - ls;
            op[16 + cl] = v1 - ls;
            if (cl < 8) op[32 + cl] = v2 - ls;
        }
    }
}

extern "C" void kernel_launch(void* const* d_in, const int* in_sizes, int n_in,
                              void* d_out, int out_size, void* d_ws, size_t ws_size,
                              hipStream_t stream) {
    const float* x      = (const float*)d_in[0];
    const int*   edge   = (const int*)d_in[1];
    const float* Wrel1  = (const float*)d_in[2];
    const float* brel1  = (const float*)d_in[3];
    const float* Wroot1 = (const float*)d_in[4];
    const float* Wrel2  = (const float*)d_in[5];
    const float* brel2  = (const float*)d_in[6];
    const float* Wroot2 = (const float*)d_in[7];
    const float* Wlin   = (const float*)d_in[8];
    const float* blin   = (const float*)d_in[9];

    const int N = in_sizes[0] / 128;
    const int E = in_sizes[1] / 2;
    const int* src = edge;
    const int* dst = edge + E;

    const int nblk  = (E + EPB - 1) / EPB;                    // 391
    const int nbuck = (N + BUCKET_SIZE - 1) / BUCKET_SIZE;    // 391

    char* ws = (char*)d_ws;
    size_t off = 0;
    auto alloc = [&](size_t bytes) -> void* {
        void* p = ws + off;
        off += (bytes + 255) & ~(size_t)255;
        return p;
    };
    unsigned short* x1bf = (unsigned short*)alloc((size_t)N * 128 * 2);
    unsigned short* x2bf = (unsigned short*)alloc((size_t)N * 128 * 2);
    unsigned short* xr   = (unsigned short*)alloc((size_t)N * 128 * 2);
    unsigned short* accbf= (unsigned short*)alloc((size_t)N * 128 * 2);
    unsigned short* bsw1 = (unsigned short*)alloc(32768 * 2);
    unsigned short* bsw2 = (unsigned short*)alloc(32768 * 2);
    unsigned short* bswL = (unsigned short*)alloc(12288 * 2);
    int* hist       = (int*)alloc((size_t)nbuck * nblk * 4);
    int* bucketTot  = (int*)alloc((size_t)nbuck * 4);
    int* bucketBase = (int*)alloc((size_t)(nbuck + 1) * 4);
    int* part       = (int*)alloc((size_t)E * 4);
    int* csr_src    = (int*)alloc((size_t)E * 4);
    int* off_       = (int*)alloc((size_t)N * 4);
    int* deg_       = (int*)alloc((size_t)N * 4);

    const int rowTiles = (N + 15) / 16;
    const int gemmBlocks = (rowTiles + 3) / 4;
    const int aggBlocks = ((N + 3) / 4) * 8;  // wave per (node, slice); slice -> XCD

    // K1: weight swizzles + edge histogram
    prep<<<304 + nblk, 256, 0, stream>>>(Wrel1, Wroot1, Wrel2, Wroot2, Wlin, dst,
                                         bsw1, bsw2, bswL, hist, E, nblk, nbuck);
    // K2: scans
    bucket_total<<<nbuck, 256, 0, stream>>>(hist, bucketTot, nblk);
    bucket_scan<<<1, 256, 0, stream>>>(bucketTot, bucketBase, nbuck);
    block_scan<<<nbuck, 256, 0, stream>>>(hist, bucketBase, nblk);
    // K3: partition
    edge_part<<<nblk, 256, 0, stream>>>(src, dst, hist, part, E, nblk, nbuck);
    // K4: CSR finalize (391 blocks) + layer-1 GEMM (independent) in one launch
    csrfin_gemm1<<<nbuck + gemmBlocks, 256, 0, stream>>>(part, bucketBase, off_, deg_, csr_src,
                                                         x, bsw1, brel1, xr, accbf, N, nbuck);
    // K5: layer-1 aggregation (sliced, wide-MLP)
    agg_sliced<<<aggBlocks, 256, 0, stream>>>(xr, accbf, off_, deg_, csr_src, x1bf, N);
    // K6: layer-2 GEMM (B in LDS, grid-stride)
    gemm_layer2<<<512, 256, 0, stream>>>(x1bf, bsw2, brel2, xr, accbf, N);
    // K7: layer-2 aggregation
    agg_sliced<<<aggBlocks, 256, 0, stream>>>(xr, accbf, off_, deg_, csr_src, x2bf, N);
    // K8: classifier + fused log_softmax (B in LDS, grid-stride)
    gemm_final_ls<<<512, 256, 0, stream>>>(x1bf, x2bf, bswL, blin, (float*)d_out, N);
}

// Round 7
// 334.886 us; speedup vs baseline: 7.1030x; 1.9522x over previous
//
#include <hip/hip_runtime.h>
#include <hip/hip_bf16.h>

typedef __attribute__((ext_vector_type(8))) short bf16x8;
typedef __attribute__((ext_vector_type(4))) float f32x4;
typedef __attribute__((ext_vector_type(2))) float f32x2;

#define EPB 4096         // edges per partition block
#define BUCKET_BITS 8
#define BUCKET_SIZE 256  // nodes per bucket
#define MAXBUCK 512

static __device__ __forceinline__ unsigned short f2bf(float f) {
    union { float f; unsigned u; } v; v.f = f;
    unsigned r = v.u + 0x7FFF + ((v.u >> 16) & 1);
    return (unsigned short)(r >> 16);
}
static __device__ __forceinline__ float asf(unsigned u) {
    union { unsigned u; float f; } v; v.u = u;
    return v.f;
}
// packed bf16 pair -> f32x2 {lo, hi}
static __device__ __forceinline__ f32x2 cvt2(unsigned u) {
    f32x2 r;
    r.x = asf(u << 16);
    r.y = asf(u & 0xFFFF0000u);
    return r;
}

// ================= K1: prep — weight swizzles + edge histogram (merged) =================
__global__ __launch_bounds__(256) void prep(const float* __restrict__ Wrel1,
                                            const float* __restrict__ Wroot1,
                                            const float* __restrict__ Wrel2,
                                            const float* __restrict__ Wroot2,
                                            const float* __restrict__ Wlin,
                                            const int* __restrict__ dst,
                                            unsigned short* __restrict__ bsw1,
                                            unsigned short* __restrict__ bsw2,
                                            unsigned short* __restrict__ bswL,
                                            int* __restrict__ hist,
                                            int E, int nblk, int nbuck) {
    __shared__ int h[MAXBUCK];
    int blk = blockIdx.x, t = threadIdx.x;
    if (blk < 256) {
        const float* Wrel  = (blk < 128) ? Wrel1 : Wrel2;
        const float* Wroot = (blk < 128) ? Wroot1 : Wroot2;
        unsigned short* bsw = (blk < 128) ? bsw1 : bsw2;
        int idx = (blk & 127) * 256 + t;  // 32768 total
        int j = idx & 7, L = (idx >> 3) & 63, ct = (idx >> 9) & 15, kt = idx >> 13;
        int k = kt * 32 + ((L >> 4) * 8) + j;
        int c = ct * 16 + (L & 15);
        float v = (c < 128) ? Wrel[k * 128 + c] : Wroot[k * 128 + (c - 128)];
        bsw[idx] = f2bf(v);
    } else if (blk < 304) {
        int idx = (blk - 256) * 256 + t;  // 12288 total
        int tt = idx;
        int j = tt & 7; tt >>= 3;
        int L = tt & 63; tt >>= 6;
        int ct = tt % 3;
        int kt = tt / 3;
        int k = kt * 32 + ((L >> 4) * 8) + j;
        int c = ct * 16 + (L & 15);
        float v = (c < 40) ? Wlin[k * 40 + c] : 0.f;
        bswL[idx] = f2bf(v);
    } else {
        int hb = blk - 304;
        for (int i = t; i < MAXBUCK; i += 256) h[i] = 0;
        __syncthreads();
        int e0 = hb * EPB;
#pragma unroll
        for (int it = 0; it < EPB / 256; it++) {
            int e = e0 + it * 256 + t;
            if (e < E) atomicAdd(&h[dst[e] >> BUCKET_BITS], 1);
        }
        __syncthreads();
        for (int i = t; i < nbuck; i += 256) hist[i * nblk + hb] = h[i];
    }
}

// ================= K2a: bucket totals =================
__global__ __launch_bounds__(256) void bucket_total(const int* __restrict__ hist,
                                                    int* __restrict__ total, int nblk) {
    __shared__ int s[256];
    int b = blockIdx.x, t = threadIdx.x;
    int v = 0;
    for (int i = t; i < nblk; i += 256) v += hist[b * nblk + i];
    s[t] = v; __syncthreads();
#pragma unroll
    for (int o = 128; o >= 1; o >>= 1) {
        if (t < o) s[t] += s[t + o];
        __syncthreads();
    }
    if (t == 0) total[b] = s[0];
}

// ================= K2b: exclusive scan of bucket totals (pair-scan, nbuck <= 512) =================
__global__ __launch_bounds__(256) void bucket_scan(const int* __restrict__ total,
                                                   int* __restrict__ base, int nbuck) {
    __shared__ int s[256];
    int t = threadIdx.x;
    int e0 = (2 * t < nbuck) ? total[2 * t] : 0;
    int e1 = (2 * t + 1 < nbuck) ? total[2 * t + 1] : 0;
    int ps = e0 + e1;
    s[t] = ps; __syncthreads();
#pragma unroll
    for (int o = 1; o < 256; o <<= 1) {
        int x = (t >= o) ? s[t - o] : 0;
        __syncthreads();
        s[t] += x; __syncthreads();
    }
    int pbase = s[t] - ps;
    if (2 * t <= nbuck) base[2 * t] = pbase;
    if (2 * t + 1 <= nbuck) base[2 * t + 1] = pbase + e0;
}

// ================= K2c: per-bucket scan over blocks -> global slot bases (in place) =================
__global__ __launch_bounds__(256) void block_scan(int* __restrict__ hist,
                                                  const int* __restrict__ base, int nblk) {
    __shared__ int s[256];
    int b = blockIdx.x, t = threadIdx.x;
    int carryv = base[b];
    for (int start = 0; start < nblk; start += 256) {
        int i = start + t;
        int v = (i < nblk) ? hist[b * nblk + i] : 0;
        s[t] = v; __syncthreads();
#pragma unroll
        for (int o = 1; o < 256; o <<= 1) {
            int x = (t >= o) ? s[t - o] : 0;
            __syncthreads();
            s[t] += x; __syncthreads();
        }
        int excl = s[t] - v + carryv;
        if (i < nblk) hist[b * nblk + i] = excl;
        carryv += s[255];
        __syncthreads();
    }
}

// ================= K3: per-chunk LDS counting sort -> bucket-sorted packed records =================
__global__ __launch_bounds__(256) void edge_part(const int* __restrict__ src,
                                                 const int* __restrict__ dst,
                                                 const int* __restrict__ hist,  // block bases
                                                 int* __restrict__ part,
                                                 int E, int nblk, int nbuck) {
    __shared__ int hcnt[MAXBUCK];
    __shared__ int lstart[MAXBUCK];
    __shared__ int cur[MAXBUCK];
    __shared__ int gbase[MAXBUCK];
    __shared__ int s2[256];
    __shared__ int sdst[EPB];  // 16 KB
    __shared__ int ssrc[EPB];  // 16 KB
    int t = threadIdx.x, blk = blockIdx.x;
    int e0 = blk * EPB;
    int cnt = E - e0; if (cnt > EPB) cnt = EPB;
    for (int i = t; i < MAXBUCK; i += 256) hcnt[i] = 0;
    for (int i = t; i < nbuck; i += 256) gbase[i] = hist[i * nblk + blk];
    __syncthreads();
    int myd[EPB / 256], mys[EPB / 256];
#pragma unroll
    for (int it = 0; it < EPB / 256; it++) {
        int i = it * 256 + t;
        if (i < cnt) {
            myd[it] = dst[e0 + i];
            mys[it] = src[e0 + i];
            atomicAdd(&hcnt[myd[it] >> BUCKET_BITS], 1);
        }
    }
    __syncthreads();
    int p0 = hcnt[2 * t], p1 = hcnt[2 * t + 1];
    int ps = p0 + p1;
    s2[t] = ps; __syncthreads();
#pragma unroll
    for (int o = 1; o < 256; o <<= 1) {
        int x = (t >= o) ? s2[t - o] : 0;
        __syncthreads();
        s2[t] += x; __syncthreads();
    }
    int pbase = s2[t] - ps;
    lstart[2 * t] = pbase; lstart[2 * t + 1] = pbase + p0;
    cur[2 * t] = 0; cur[2 * t + 1] = 0;
    __syncthreads();
#pragma unroll
    for (int it = 0; it < EPB / 256; it++) {
        int i = it * 256 + t;
        if (i < cnt) {
            int b = myd[it] >> BUCKET_BITS;
            int p = lstart[b] + atomicAdd(&cur[b], 1);
            sdst[p] = myd[it];
            ssrc[p] = mys[it];
        }
    }
    __syncthreads();
    for (int i = t; i < cnt; i += 256) {
        int d = sdst[i], s = ssrc[i];
        int b = d >> BUCKET_BITS;
        part[gbase[b] + (i - lstart[b])] = ((d & (BUCKET_SIZE - 1)) << 17) | s;
    }
}

// ================= K4: csr_finalize (blocks 0..nbuck-1) + layer-1 GEMM (rest), merged =================
// GEMM branch now stages B in LDS (64 KB): kills the 400 MB L2->L1 B re-read
// (each wave previously streamed the whole 64 KB B from global per tile).
__global__ __launch_bounds__(256) void csrfin_gemm1(const int* __restrict__ part,
                                                    const int* __restrict__ bucketBase,
                                                    int* __restrict__ off_,
                                                    int* __restrict__ deg_,
                                                    int* __restrict__ csr_src,
                                                    const float* __restrict__ x,
                                                    const unsigned short* __restrict__ Bsw,
                                                    const float* __restrict__ bias,
                                                    unsigned short* __restrict__ xr,
                                                    unsigned short* __restrict__ accbf,
                                                    int N, int nbuck) {
    __shared__ unsigned short Bs[32768];  // 64 KB (GEMM branch)
    __shared__ int cur[BUCKET_SIZE];
    __shared__ int h[BUCKET_SIZE];
    __shared__ int tsum[256];
    int t = threadIdx.x;
    if (blockIdx.x < (unsigned)nbuck) {
        int b = blockIdx.x;
        int lo = bucketBase[b], hi = bucketBase[b + 1];
        int n0 = b * BUCKET_SIZE;
        h[t] = 0;
        __syncthreads();
        for (int i = lo + t; i < hi; i += 256) atomicAdd(&h[part[i] >> 17], 1);
        __syncthreads();
        int hv = h[t];
        tsum[t] = hv;
        __syncthreads();
#pragma unroll
        for (int o = 1; o < 256; o <<= 1) {
            int xx = (t >= o) ? tsum[t - o] : 0;
            __syncthreads();
            tsum[t] += xx;
            __syncthreads();
        }
        int st = tsum[t] - hv;
        cur[t] = st;
        int node = n0 + t;
        if (node < N) { off_[node] = lo + st; deg_[node] = hv; }
        __syncthreads();
        for (int i = lo + t; i < hi; i += 256) {
            int rec = part[i];
            int p = atomicAdd(&cur[rec >> 17], 1);
            csr_src[lo + p] = rec & 0x1FFFF;
        }
    } else {
        // stage B into LDS (block-uniform branch -> __syncthreads is safe)
        {
            uint4* d4 = (uint4*)Bs;
            const uint4* s4 = (const uint4*)Bsw;
#pragma unroll
            for (int i = 0; i < 16; i++) d4[t + i * 256] = s4[t + i * 256];
        }
        __syncthreads();
        int wid = (blockIdx.x - nbuck) * 4 + (t >> 6);
        int L = t & 63;
        int r0 = wid * 16;
        if (r0 >= N) return;
        int arow = r0 + (L & 15);
        f32x4 acc[16];
#pragma unroll
        for (int i = 0; i < 16; i++) acc[i] = (f32x4){0.f, 0.f, 0.f, 0.f};
#pragma unroll
        for (int kt = 0; kt < 4; kt++) {
            const float* Arow = x + (size_t)arow * 128 + ((L >> 4) * 8) + kt * 32;
            float4 a0 = *(const float4*)Arow;
            float4 a1 = *(const float4*)(Arow + 4);
            bf16x8 a;
            a[0] = (short)f2bf(a0.x); a[1] = (short)f2bf(a0.y);
            a[2] = (short)f2bf(a0.z); a[3] = (short)f2bf(a0.w);
            a[4] = (short)f2bf(a1.x); a[5] = (short)f2bf(a1.y);
            a[6] = (short)f2bf(a1.z); a[7] = (short)f2bf(a1.w);
#pragma unroll
            for (int ct = 0; ct < 16; ct++) {
                bf16x8 b = *(const bf16x8*)(Bs + (((kt * 16 + ct) * 64) + L) * 8);
                acc[ct] = __builtin_amdgcn_mfma_f32_16x16x32_bf16(a, b, acc[ct], 0, 0, 0);
            }
        }
        int rbase = r0 + (L >> 4) * 4;
        int cl = L & 15;
#pragma unroll
        for (int ct = 0; ct < 16; ct++) {
            int col = ct * 16 + cl;
#pragma unroll
            for (int r = 0; r < 4; r++) {
                int row = rbase + r;
                float v = acc[ct][r];
                if (col < 128)
                    xr[(size_t)row * 128 + col] = f2bf(v);
                else
                    accbf[(size_t)row * 128 + (col - 128)] = f2bf(v + bias[col - 128]);
            }
        }
    }
}

// ================= layer-2 GEMM (bf16 A, B staged in LDS, grid-stride tiles) =================
__global__ __launch_bounds__(256) void gemm_layer2(const unsigned short* __restrict__ Abf,
                                                   const unsigned short* __restrict__ Bsw,
                                                   const float* __restrict__ bias,
                                                   unsigned short* __restrict__ xr,
                                                   unsigned short* __restrict__ accbf, int N) {
    __shared__ unsigned short Bs[32768];  // 64 KB
    int t = threadIdx.x;
    {
        uint4* d4 = (uint4*)Bs;
        const uint4* s4 = (const uint4*)Bsw;
#pragma unroll
        for (int i = 0; i < 16; i++) d4[t + i * 256] = s4[t + i * 256];
    }
    __syncthreads();
    int w = t >> 6, L = t & 63;
    int nTiles = (N + 15) / 16;
    for (int tile = blockIdx.x * 4 + w; tile < nTiles; tile += gridDim.x * 4) {
        int r0 = tile * 16;
        int arow = r0 + (L & 15);
        f32x4 acc[16];
#pragma unroll
        for (int i = 0; i < 16; i++) acc[i] = (f32x4){0.f, 0.f, 0.f, 0.f};
#pragma unroll
        for (int kt = 0; kt < 4; kt++) {
            bf16x8 a = *((const bf16x8*)(Abf + (size_t)arow * 128 + ((L >> 4) * 8) + kt * 32));
#pragma unroll
            for (int ct = 0; ct < 16; ct++) {
                bf16x8 b = *(const bf16x8*)(Bs + (((kt * 16 + ct) * 64) + L) * 8);
                acc[ct] = __builtin_amdgcn_mfma_f32_16x16x32_bf16(a, b, acc[ct], 0, 0, 0);
            }
        }
        int rbase = r0 + (L >> 4) * 4;
        int cl = L & 15;
#pragma unroll
        for (int ct = 0; ct < 16; ct++) {
            int col = ct * 16 + cl;
#pragma unroll
            for (int r = 0; r < 4; r++) {
                int row = rbase + r;
                float v = acc[ct][r];
                if (col < 128)
                    xr[(size_t)row * 128 + col] = f2bf(v);
                else
                    accbf[(size_t)row * 128 + (col - 128)] = f2bf(v + bias[col - 128]);
            }
        }
    }
}

// ================= gather-aggregate + relu + bf16 convert (R0 structure, verbatim) =================
// one wave per node; 4 edges per dwordx4 load; f32x2 accumulators -> v_pk_add_f32
__global__ __launch_bounds__(256) void agg_relu_cvt(const unsigned short* __restrict__ xr,
                                                    const unsigned short* __restrict__ accbf,
                                                    const int* __restrict__ off_,
                                                    const int* __restrict__ deg,
                                                    const int* __restrict__ csr_src,
                                                    unsigned short* __restrict__ out, int N) {
    int node = blockIdx.x * 4 + (threadIdx.x >> 6);
    if (node >= N) return;
    int L = threadIdx.x & 63;
    int g = L >> 4;
    int f = L & 15;
    int o = off_[node];
    int d = deg[node];
    uint4 arow = (uint4){0, 0, 0, 0};
    if (g == 0) arow = *(const uint4*)(accbf + (size_t)node * 128 + f * 8);

    const int* ip = csr_src + o + g;
    const unsigned short* xrf = xr + f * 8;

    f32x2 a0 = (f32x2){0.f, 0.f}, a1 = (f32x2){0.f, 0.f};
    f32x2 a2 = (f32x2){0.f, 0.f}, a3 = (f32x2){0.f, 0.f};

    int d4 = d & ~3;
#pragma unroll 4
    for (int k = 0; k < d4; k += 4) {
        int s = ip[k];  // group-uniform (16 lanes same addr -> broadcast)
        uint4 p = *(const uint4*)(xrf + (size_t)s * 128);
        a0 += cvt2(p.x);
        a1 += cvt2(p.y);
        a2 += cvt2(p.z);
        a3 += cvt2(p.w);
    }
    if (d4 + g < d) {
        int s = ip[d4];
        uint4 p = *(const uint4*)(xrf + (size_t)s * 128);
        a0 += cvt2(p.x);
        a1 += cvt2(p.y);
        a2 += cvt2(p.z);
        a3 += cvt2(p.w);
    }
    a0.x += __shfl_xor(a0.x, 16, 64); a0.y += __shfl_xor(a0.y, 16, 64);
    a1.x += __shfl_xor(a1.x, 16, 64); a1.y += __shfl_xor(a1.y, 16, 64);
    a2.x += __shfl_xor(a2.x, 16, 64); a2.y += __shfl_xor(a2.y, 16, 64);
    a3.x += __shfl_xor(a3.x, 16, 64); a3.y += __shfl_xor(a3.y, 16, 64);
    a0.x += __shfl_xor(a0.x, 32, 64); a0.y += __shfl_xor(a0.y, 32, 64);
    a1.x += __shfl_xor(a1.x, 32, 64); a1.y += __shfl_xor(a1.y, 32, 64);
    a2.x += __shfl_xor(a2.x, 32, 64); a2.y += __shfl_xor(a2.y, 32, 64);
    a3.x += __shfl_xor(a3.x, 32, 64); a3.y += __shfl_xor(a3.y, 32, 64);

    if (g == 0) {
        uint4 wv;
        wv.x = ((unsigned)f2bf(fmaxf(asf(arow.x & 0xFFFF0000u) + a0.y, 0.f)) << 16)
             | f2bf(fmaxf(asf(arow.x << 16) + a0.x, 0.f));
        wv.y = ((unsigned)f2bf(fmaxf(asf(arow.y & 0xFFFF0000u) + a1.y, 0.f)) << 16)
             | f2bf(fmaxf(asf(arow.y << 16) + a1.x, 0.f));
        wv.z = ((unsigned)f2bf(fmaxf(asf(arow.z & 0xFFFF0000u) + a2.y, 0.f)) << 16)
             | f2bf(fmaxf(asf(arow.z << 16) + a2.x, 0.f));
        wv.w = ((unsigned)f2bf(fmaxf(asf(arow.w & 0xFFFF0000u) + a3.y, 0.f)) << 16)
             | f2bf(fmaxf(asf(arow.w << 16) + a3.x, 0.f));
        *(uint4*)(out + (size_t)node * 128 + f * 8) = wv;
    }
}

// ================= final GEMM + fused log_softmax (B in LDS, grid-stride) =================
__global__ __launch_bounds__(256) void gemm_final_ls(const unsigned short* __restrict__ x1bf,
                                                     const unsigned short* __restrict__ x2bf,
                                                     const unsigned short* __restrict__ Bsw,
                                                     const float* __restrict__ blin,
                                                     float* __restrict__ out, int N) {
    __shared__ unsigned short Bs[12288];  // 24 KB
    int t = threadIdx.x;
    {
        uint4* d4 = (uint4*)Bs;
        const uint4* s4 = (const uint4*)Bsw;
#pragma unroll
        for (int i = 0; i < 6; i++) d4[t + i * 256] = s4[t + i * 256];
    }
    __syncthreads();
    int w = t >> 6, L = t & 63;
    int cl = L & 15;
    float b0 = blin[cl], b1 = blin[16 + cl];
    float b2 = (cl < 8) ? blin[32 + cl] : 0.f;
    int nTiles = (N + 15) / 16;
    for (int tile = blockIdx.x * 4 + w; tile < nTiles; tile += gridDim.x * 4) {
        int r0 = tile * 16;
        int arow = r0 + (L & 15);
        f32x4 acc[3];
#pragma unroll
        for (int i = 0; i < 3; i++) acc[i] = (f32x4){0.f, 0.f, 0.f, 0.f};
#pragma unroll
        for (int kt = 0; kt < 8; kt++) {
            const unsigned short* Ab = (kt < 4) ? x1bf : x2bf;
            int kk = (kt & 3) * 32 + ((L >> 4) * 8);
            bf16x8 a = *((const bf16x8*)(Ab + (size_t)arow * 128 + kk));
#pragma unroll
            for (int ct = 0; ct < 3; ct++) {
                bf16x8 b = *(const bf16x8*)(Bs + (((kt * 3 + ct) * 64) + L) * 8);
                acc[ct] = __builtin_amdgcn_mfma_f32_16x16x32_bf16(a, b, acc[ct], 0, 0, 0);
            }
        }
        int rbase = r0 + (L >> 4) * 4;
#pragma unroll
        for (int r = 0; r < 4; r++) {
            int row = rbase + r;
            float v0 = acc[0][r] + b0;
            float v1 = acc[1][r] + b1;
            float v2 = (cl < 8) ? (acc[2][r] + b2) : -__builtin_inff();
            float m = fmaxf(fmaxf(v0, v1), v2);
#pragma unroll
            for (int off = 8; off >= 1; off >>= 1) m = fmaxf(m, __shfl_xor(m, off, 64));
            float e = __expf(v0 - m) + __expf(v1 - m) + ((cl < 8) ? __expf(v2 - m) : 0.f);
#pragma unroll
            for (int off = 8; off >= 1; off >>= 1) e += __shfl_xor(e, off, 64);
            float ls = m + __logf(e);
            float* op = out + (size_t)row * 40;
            op[cl] = v0 - ls;
            op[16 + cl] = v1 - ls;
            if (cl < 8) op[32 + cl] = v2 - ls;
        }
    }
}

extern "C" void kernel_launch(void* const* d_in, const int* in_sizes, int n_in,
                              void* d_out, int out_size, void* d_ws, size_t ws_size,
                              hipStream_t stream) {
    const float* x      = (const float*)d_in[0];
    const int*   edge   = (const int*)d_in[1];
    const float* Wrel1  = (const float*)d_in[2];
    const float* brel1  = (const float*)d_in[3];
    const float* Wroot1 = (const float*)d_in[4];
    const float* Wrel2  = (const float*)d_in[5];
    const float* brel2  = (const float*)d_in[6];
    const float* Wroot2 = (const float*)d_in[7];
    const float* Wlin   = (const float*)d_in[8];
    const float* blin   = (const float*)d_in[9];

    const int N = in_sizes[0] / 128;
    const int E = in_sizes[1] / 2;
    const int* src = edge;
    const int* dst = edge + E;

    const int nblk  = (E + EPB - 1) / EPB;                    // 391
    const int nbuck = (N + BUCKET_SIZE - 1) / BUCKET_SIZE;    // 391

    char* ws = (char*)d_ws;
    size_t off = 0;
    auto alloc = [&](size_t bytes) -> void* {
        void* p = ws + off;
        off += (bytes + 255) & ~(size_t)255;
        return p;
    };
    unsigned short* x1bf = (unsigned short*)alloc((size_t)N * 128 * 2);
    unsigned short* x2bf = (unsigned short*)alloc((size_t)N * 128 * 2);
    unsigned short* xr   = (unsigned short*)alloc((size_t)N * 128 * 2);
    unsigned short* accbf= (unsigned short*)alloc((size_t)N * 128 * 2);
    unsigned short* bsw1 = (unsigned short*)alloc(32768 * 2);
    unsigned short* bsw2 = (unsigned short*)alloc(32768 * 2);
    unsigned short* bswL = (unsigned short*)alloc(12288 * 2);
    int* hist       = (int*)alloc((size_t)nbuck * nblk * 4);
    int* bucketTot  = (int*)alloc((size_t)nbuck * 4);
    int* bucketBase = (int*)alloc((size_t)(nbuck + 1) * 4);
    int* part       = (int*)alloc((size_t)E * 4);
    int* csr_src    = (int*)alloc((size_t)E * 4);
    int* off_       = (int*)alloc((size_t)N * 4);
    int* deg_       = (int*)alloc((size_t)N * 4);

    const int rowTiles = (N + 15) / 16;
    const int gemmBlocks = (rowTiles + 3) / 4;
    const int nodeBlocks = (N + 3) / 4;

    // K1: weight swizzles + edge histogram
    prep<<<304 + nblk, 256, 0, stream>>>(Wrel1, Wroot1, Wrel2, Wroot2, Wlin, dst,
                                         bsw1, bsw2, bswL, hist, E, nblk, nbuck);
    // K2: scans
    bucket_total<<<nbuck, 256, 0, stream>>>(hist, bucketTot, nblk);
    bucket_scan<<<1, 256, 0, stream>>>(bucketTot, bucketBase, nbuck);
    block_scan<<<nbuck, 256, 0, stream>>>(hist, bucketBase, nblk);
    // K3: partition
    edge_part<<<nblk, 256, 0, stream>>>(src, dst, hist, part, E, nblk, nbuck);
    // K4: CSR finalize (391 blocks) + layer-1 GEMM (LDS-staged B) in one launch
    csrfin_gemm1<<<nbuck + gemmBlocks, 256, 0, stream>>>(part, bucketBase, off_, deg_, csr_src,
                                                         x, bsw1, brel1, xr, accbf, N, nbuck);
    // K5: layer-1 aggregation
    agg_relu_cvt<<<nodeBlocks, 256, 0, stream>>>(xr, accbf, off_, deg_, csr_src, x1bf, N);
    // K6: layer-2 GEMM (B in LDS, grid-stride)
    gemm_layer2<<<512, 256, 0, stream>>>(x1bf, bsw2, brel2, xr, accbf, N);
    // K7: layer-2 aggregation
    agg_relu_cvt<<<nodeBlocks, 256, 0, stream>>>(xr, accbf, off_, deg_, csr_src, x2bf, N);
    // K8: classifier + fused log_softmax (B in LDS, grid-stride)
    gemm_final_ls<<<512, 256, 0, stream>>>(x1bf, x2bf, bswL, blin, (float*)d_out, N);
}